// Round 1
// baseline (847.338 us; speedup 1.0000x reference)
//
#include <hip/hip_runtime.h>

#define TLEN 100
#define ECN  100
#define CA1N 100
#define CA3N 100
#define BSZ  4096
#define ACTN 2
#define BT   8      // batch rows per block
#define WP   108    // bf16 weight row pad (elements)
#define SP   104    // fp32 state row pad (elements, 16B-aligned rows)

__device__ __forceinline__ float bf2f(unsigned short u){
  union { unsigned int i; float f; } c; c.i = ((unsigned int)u) << 16; return c.f;
}
__device__ __forceinline__ unsigned short f2bf(float f){
  union { float f; unsigned int u; } c; c.f = f;
  unsigned int u = c.u;
  // round-to-nearest-even bf16 truncation (weights are finite, no NaN handling needed)
  unsigned int r = (u + 0x7FFFu + ((u >> 16) & 1u)) >> 16;
  return (unsigned short)r;
}
__device__ __forceinline__ float sigm(float x){ return 1.0f / (1.0f + __expf(-x)); }

// ---- kernel 0: drive[t][j] = sum_k exp(-((t-c_k)/5)^2/2) * Wca3ca1[k][j] ----
__global__ void drive_kernel(const float* __restrict__ Wca3ca1, float* __restrict__ drive){
  __shared__ float ca3row[CA3N];
  const int t = blockIdx.x, tid = threadIdx.x;
  if (tid < CA3N){
    float c = (float)tid * (100.0f / 99.0f);   // linspace(0,100,100)
    float d = ((float)t - c) * 0.2f;           // /SIGMA=5
    ca3row[tid] = __expf(-0.5f * d * d);
  }
  __syncthreads();
  if (tid < CA1N){
    float acc = 0.f;
    for (int k = 0; k < CA3N; ++k) acc = fmaf(ca3row[k], Wca3ca1[k*CA1N + tid], acc);
    drive[t*CA1N + tid] = acc;
  }
}

// ---- main persistent RNN kernel: each block owns BT batch rows, loops all T ----
__global__ __launch_bounds__(256, 2)
void rnn_kernel(const int*   __restrict__ cue_train,
                const float* __restrict__ ec3_last,
                const float* __restrict__ ec5_last,
                const float* __restrict__ cueL,
                const float* __restrict__ cueR,
                const float* __restrict__ Wec3ca1,
                const float* __restrict__ Wca1ec5,
                const float* __restrict__ Wca1act,
                const float* __restrict__ ca1bias,
                const float* __restrict__ drive,
                float*       __restrict__ out)
{
  __shared__ __align__(16) unsigned short W1T[CA1N * WP]; // W1T[j][i] = Wec3ca1[i][j]  (bf16)
  __shared__ __align__(16) unsigned short W2T[ECN  * WP]; // W2T[e][j] = Wca1ec5[j][e]  (bf16)
  __shared__ __align__(16) float ec3s[BT * SP];
  __shared__ __align__(16) float ec5s[BT * SP];
  __shared__ __align__(16) float ca1s[BT * SP];
  __shared__ float biasS[CA1N];
  __shared__ float cueLS[ECN];
  __shared__ float cueRS[ECN];
  __shared__ signed char cueT[BT * TLEN];

  const int tid = threadIdx.x;
  const int b0  = blockIdx.x * BT;

  float* out_act = out;
  float* out_his = out + (size_t)BSZ * ACTN;
  float* out_e3  = out_his + (size_t)TLEN * BSZ * CA1N;
  float* out_e5  = out_e3 + (size_t)BSZ * ECN;
  float* out_c1  = out_e5 + (size_t)BSZ * ECN;

  // --- stage weights (bf16, transposed) and state into LDS ---
  for (int idx = tid; idx < ECN * CA1N; idx += 256){
    int row = idx / CA1N, col = idx - row * CA1N;   // row = input dim, col = output dim
    W1T[col * WP + row] = f2bf(Wec3ca1[idx]);
    W2T[col * WP + row] = f2bf(Wca1ec5[idx]);
  }
  for (int idx = tid; idx < BT * ECN; idx += 256){
    int r = idx / ECN, i = idx - r * ECN;
    ec3s[r * SP + i] = ec3_last[(size_t)(b0 + r) * ECN + i];
    ec5s[r * SP + i] = ec5_last[(size_t)(b0 + r) * ECN + i];
  }
  for (int idx = tid; idx < BT * TLEN; idx += 256){
    int r = idx / TLEN, tt = idx - r * TLEN;
    cueT[r * TLEN + tt] = (signed char)cue_train[(size_t)(b0 + r) * TLEN + tt];
  }
  if (tid < CA1N) biasS[tid] = ca1bias[tid];
  if (tid < ECN){ cueLS[tid] = cueL[tid]; cueRS[tid] = cueR[tid]; }
  __syncthreads();

  const int j   = tid & 127;        // output column (CA1 idx in phase1, EC idx in phase2)
  const int rg  = tid >> 7;         // row group 0/1
  const int r0  = rg * 4;
  const bool active = (j < CA1N);

  for (int t = 0; t < TLEN; ++t){
    // ---- phase 1: z = ec3 @ W1 ; ca1 = relu(drive*(1+sig(z)) - bias) ----
    if (active){
      float a0 = 0.f, a1 = 0.f, a2 = 0.f, a3 = 0.f;
      const unsigned short* wr = &W1T[j * WP];
      const float* e0 = &ec3s[(r0 + 0) * SP];
      const float* e1 = &ec3s[(r0 + 1) * SP];
      const float* e2 = &ec3s[(r0 + 2) * SP];
      const float* e3 = &ec3s[(r0 + 3) * SP];
      #pragma unroll 5
      for (int i = 0; i < ECN; i += 4){
        ushort4 wu = *reinterpret_cast<const ushort4*>(wr + i);
        float wx = bf2f(wu.x), wy = bf2f(wu.y), wz = bf2f(wu.z), wv = bf2f(wu.w);
        float4 v0 = *reinterpret_cast<const float4*>(e0 + i);
        float4 v1 = *reinterpret_cast<const float4*>(e1 + i);
        float4 v2 = *reinterpret_cast<const float4*>(e2 + i);
        float4 v3 = *reinterpret_cast<const float4*>(e3 + i);
        a0 = fmaf(v0.x,wx, fmaf(v0.y,wy, fmaf(v0.z,wz, fmaf(v0.w,wv, a0))));
        a1 = fmaf(v1.x,wx, fmaf(v1.y,wy, fmaf(v1.z,wz, fmaf(v1.w,wv, a1))));
        a2 = fmaf(v2.x,wx, fmaf(v2.y,wy, fmaf(v2.z,wz, fmaf(v2.w,wv, a2))));
        a3 = fmaf(v3.x,wx, fmaf(v3.y,wy, fmaf(v3.z,wz, fmaf(v3.w,wv, a3))));
      }
      float dj = drive[t * CA1N + j];
      float bj = biasS[j];
      float c0 = fmaxf(fmaf(dj, 1.0f + sigm(a0), -bj), 0.f);
      float c1 = fmaxf(fmaf(dj, 1.0f + sigm(a1), -bj), 0.f);
      float c2 = fmaxf(fmaf(dj, 1.0f + sigm(a2), -bj), 0.f);
      float c3 = fmaxf(fmaf(dj, 1.0f + sigm(a3), -bj), 0.f);
      size_t ob = (size_t)t * (BSZ * CA1N) + (size_t)(b0 + r0) * CA1N + j;
      ca1s[(r0 + 0) * SP + j] = c0; out_his[ob           ] = c0;
      ca1s[(r0 + 1) * SP + j] = c1; out_his[ob +     CA1N] = c1;
      ca1s[(r0 + 2) * SP + j] = c2; out_his[ob + 2 * CA1N] = c2;
      ca1s[(r0 + 3) * SP + j] = c3; out_his[ob + 3 * CA1N] = c3;
    }
    __syncthreads();

    // ---- phase 2: delta = ca1 @ W2 ; ec5 = g(ec5+delta) ; ec3 = ec5*ec3 + sensory ----
    if (active){
      float d0 = 0.f, d1 = 0.f, d2 = 0.f, d3 = 0.f;
      const unsigned short* w2r = &W2T[j * WP];
      const float* p0 = &ca1s[(r0 + 0) * SP];
      const float* p1 = &ca1s[(r0 + 1) * SP];
      const float* p2 = &ca1s[(r0 + 2) * SP];
      const float* p3 = &ca1s[(r0 + 3) * SP];
      #pragma unroll 5
      for (int jj = 0; jj < CA1N; jj += 4){
        ushort4 wu = *reinterpret_cast<const ushort4*>(w2r + jj);
        float wx = bf2f(wu.x), wy = bf2f(wu.y), wz = bf2f(wu.z), wv = bf2f(wu.w);
        float4 v0 = *reinterpret_cast<const float4*>(p0 + jj);
        float4 v1 = *reinterpret_cast<const float4*>(p1 + jj);
        float4 v2 = *reinterpret_cast<const float4*>(p2 + jj);
        float4 v3 = *reinterpret_cast<const float4*>(p3 + jj);
        d0 = fmaf(v0.x,wx, fmaf(v0.y,wy, fmaf(v0.z,wz, fmaf(v0.w,wv, d0))));
        d1 = fmaf(v1.x,wx, fmaf(v1.y,wy, fmaf(v1.z,wz, fmaf(v1.w,wv, d1))));
        d2 = fmaf(v2.x,wx, fmaf(v2.y,wy, fmaf(v2.z,wz, fmaf(v2.w,wv, d2))));
        d3 = fmaf(v3.x,wx, fmaf(v3.y,wy, fmaf(v3.z,wz, fmaf(v3.w,wv, d3))));
      }
      int cu0 = cueT[(r0 + 0) * TLEN + t];
      int cu1 = cueT[(r0 + 1) * TLEN + t];
      int cu2 = cueT[(r0 + 2) * TLEN + t];
      int cu3 = cueT[(r0 + 3) * TLEN + t];
      float dd[4] = {d0, d1, d2, d3};
      int   cc[4] = {cu0, cu1, cu2, cu3};
      #pragma unroll
      for (int rr = 0; rr < 4; ++rr){
        int r = r0 + rr;
        float x  = ec5s[r * SP + j] + dd[rr];
        float e5 = fmaf(0.3f, sigm(fmaf(4.0f, x, -1.2f)), 0.69f);
        ec5s[r * SP + j] = e5;
        int cu = cc[rr];
        float sns = (cu == 1) ? cueLS[j] : ((cu == -1) ? cueRS[j] : 0.0f);
        ec3s[r * SP + j] = fmaf(e5, ec3s[r * SP + j], sns);
      }
    }
    __syncthreads();
  }

  // ---- epilogue: actCell = ca1_final @ Wca1act ; dump final states ----
  if (tid < BT * ACTN){
    int r = tid >> 1, a = tid & 1;
    float acc = 0.f;
    for (int jj = 0; jj < CA1N; ++jj)
      acc = fmaf(ca1s[r * SP + jj], Wca1act[jj * ACTN + a], acc);
    out_act[(size_t)(b0 + r) * ACTN + a] = acc;
  }
  for (int idx = tid; idx < BT * ECN; idx += 256){
    int r = idx / ECN, i = idx - r * ECN;
    size_t g = (size_t)(b0 + r) * ECN + i;
    out_e3[g] = ec3s[r * SP + i];
    out_e5[g] = ec5s[r * SP + i];
    out_c1[g] = ca1s[r * SP + i];
  }
}

extern "C" void kernel_launch(void* const* d_in, const int* in_sizes, int n_in,
                              void* d_out, int out_size, void* d_ws, size_t ws_size,
                              hipStream_t stream) {
  (void)in_sizes; (void)n_in; (void)out_size; (void)ws_size;
  const int*   cue_train = (const int*)  d_in[1];
  const float* ec3_last  = (const float*)d_in[2];
  const float* ec5_last  = (const float*)d_in[3];
  const float* cueL      = (const float*)d_in[5];
  const float* cueR      = (const float*)d_in[6];
  const float* Wec3ca1   = (const float*)d_in[7];
  const float* Wca3ca1   = (const float*)d_in[8];
  const float* Wca1ec5   = (const float*)d_in[9];
  const float* Wca1act   = (const float*)d_in[10];
  const float* ca1bias   = (const float*)d_in[11];
  float* out   = (float*)d_out;
  float* drive = (float*)d_ws;   // 100*100 fp32 = 40 KB scratch

  drive_kernel<<<TLEN, 128, 0, stream>>>(Wca3ca1, drive);
  rnn_kernel<<<BSZ / BT, 256, 0, stream>>>(cue_train, ec3_last, ec5_last,
                                           cueL, cueR, Wec3ca1, Wca1ec5,
                                           Wca1act, ca1bias, drive, out);
}

// Round 2
// 289.844 us; speedup vs baseline: 2.9234x; 2.9234x over previous
//
#include <hip/hip_runtime.h>

#define TLEN 100
#define ECN  100
#define CA1N 100
#define CA3N 100
#define BSZ  4096
#define ACTN 2
#define BT   16     // batch rows per block (= MFMA M)
#define SPF  132    // fp32 state row stride (floats)
#define SPB  136    // bf16 state row stride (shorts), cols 100..135 zero pad

typedef short bf16x8 __attribute__((ext_vector_type(8)));
typedef float f32x4  __attribute__((ext_vector_type(4)));

__device__ __forceinline__ unsigned short f2bf(float f){
  union { float f; unsigned int u; } c; c.f = f;
  unsigned int u = c.u;
  unsigned int r = (u + 0x7FFFu + ((u >> 16) & 1u)) >> 16; // RNE
  return (unsigned short)r;
}
__device__ __forceinline__ float sigm(float x){ return 1.0f / (1.0f + __expf(-x)); }

// ---- kernel 0: drive[t][j] = sum_k exp(-((t-c_k)/5)^2/2) * Wca3ca1[k][j] ----
__global__ void drive_kernel(const float* __restrict__ Wca3ca1, float* __restrict__ drive){
  __shared__ float ca3row[CA3N];
  const int t = blockIdx.x, tid = threadIdx.x;
  if (tid < CA3N){
    float c = (float)tid * (100.0f / 99.0f);   // linspace(0,100,100)
    float d = ((float)t - c) * 0.2f;           // /SIGMA=5
    ca3row[tid] = __expf(-0.5f * d * d);
  }
  __syncthreads();
  if (tid < CA1N){
    float acc = 0.f;
    for (int k = 0; k < CA3N; ++k) acc = fmaf(ca3row[k], Wca3ca1[k*CA1N + tid], acc);
    drive[t*CA1N + tid] = acc;
  }
}

// ---- main persistent MFMA RNN kernel ----
__global__ __launch_bounds__(512, 1)
void rnn_kernel(const int*   __restrict__ cue_train,
                const float* __restrict__ ec3_last,
                const float* __restrict__ ec5_last,
                const float* __restrict__ cueL,
                const float* __restrict__ cueR,
                const float* __restrict__ Wec3ca1,
                const float* __restrict__ Wca1ec5,
                const float* __restrict__ Wca1act,
                const float* __restrict__ ca1bias,
                const float* __restrict__ drive,
                float*       __restrict__ out)
{
  __shared__ __align__(16) float ec3f[BT * SPF];          // fp32 master state
  __shared__ __align__(16) float ec5f[BT * SPF];
  __shared__ __align__(16) float ca1f[BT * SPF];          // final-step ca1 (epilogue only)
  __shared__ __align__(16) unsigned short ec3b[BT * SPB]; // bf16 shadow (A-operand source)
  __shared__ __align__(16) unsigned short ca1b[BT * SPB];
  __shared__ signed char cueT[TLEN * BT];                 // cue transposed [t][r]

  const int tid = threadIdx.x;
  const int b0  = blockIdx.x * BT;

  float* out_act = out;
  float* out_his = out + (size_t)BSZ * ACTN;
  float* out_e3  = out_his + (size_t)TLEN * BSZ * CA1N;
  float* out_e5  = out_e3 + (size_t)BSZ * ECN;
  float* out_c1  = out_e5 + (size_t)BSZ * ECN;

  // --- zero bf16 shadows (pad cols must stay 0: they feed MFMA K/N padding) ---
  for (int idx = tid; idx < BT * SPB; idx += 512){ ec3b[idx] = 0; ca1b[idx] = 0; }
  __syncthreads();

  // --- stage state + cue ---
  for (int idx = tid; idx < BT * ECN; idx += 512){
    int r = idx / ECN, c = idx - r * ECN;
    float v3 = ec3_last[(size_t)(b0 + r) * ECN + c];
    ec3f[r * SPF + c] = v3;
    ec3b[r * SPB + c] = f2bf(v3);
    ec5f[r * SPF + c] = ec5_last[(size_t)(b0 + r) * ECN + c];
  }
  for (int idx = tid; idx < BT * TLEN; idx += 512){
    int t = idx >> 4, r = idx & 15;
    cueT[idx] = (signed char)cue_train[(size_t)(b0 + r) * TLEN + t];
  }

  // --- per-lane constants & B-fragments (weights in registers, bf16) ---
  const int lane  = tid & 63;
  const int wv    = tid >> 6;        // wave id = N-tile id (0..7)
  const int col16 = lane & 15;
  const int q     = lane >> 4;       // quad
  const int col   = wv * 16 + col16; // output column (CA1 idx ph1, EC idx ph2)
  const bool okc  = (col < CA1N);

  bf16x8 b1[4], b2[4];               // B-frags: [n=lane&15][k=q*8+j], k = ks*32+q*8+j
  #pragma unroll
  for (int ks = 0; ks < 4; ++ks){
    #pragma unroll
    for (int jj = 0; jj < 8; ++jj){
      int k = ks * 32 + q * 8 + jj;
      float w1 = 0.f, w2 = 0.f;
      if (k < ECN && okc){
        w1 = Wec3ca1[k * CA1N + col];
        w2 = Wca1ec5[k * ECN  + col];
      }
      b1[ks][jj] = (short)f2bf(w1);
      b2[ks][jj] = (short)f2bf(w2);
    }
  }
  float bias_c = 0.f, cL = 0.f, cR = 0.f;
  if (okc){ bias_c = ca1bias[col]; cL = cueL[col]; cR = cueR[col]; }
  __syncthreads();

  const int m = col16;               // A-operand row for this lane
  const unsigned short* arow1 = &ec3b[m * SPB];
  const unsigned short* arow2 = &ca1b[m * SPB];

  for (int t = 0; t < TLEN; ++t){
    // issue drive load early; used after MFMAs
    float dv = okc ? drive[t * CA1N + col] : 0.f;

    // ---- phase 1: z = ec3 @ W1 (MFMA), ca1 = relu(d*(1+sig(z)) - bias) ----
    f32x4 accA = {0.f,0.f,0.f,0.f}, accB = {0.f,0.f,0.f,0.f};
    {
      bf16x8 a0 = *reinterpret_cast<const bf16x8*>(arow1 +  0 + q * 8);
      bf16x8 a1 = *reinterpret_cast<const bf16x8*>(arow1 + 32 + q * 8);
      bf16x8 a2 = *reinterpret_cast<const bf16x8*>(arow1 + 64 + q * 8);
      bf16x8 a3 = *reinterpret_cast<const bf16x8*>(arow1 + 96 + q * 8);
      accA = __builtin_amdgcn_mfma_f32_16x16x32_bf16(a0, b1[0], accA, 0, 0, 0);
      accB = __builtin_amdgcn_mfma_f32_16x16x32_bf16(a1, b1[1], accB, 0, 0, 0);
      accA = __builtin_amdgcn_mfma_f32_16x16x32_bf16(a2, b1[2], accA, 0, 0, 0);
      accB = __builtin_amdgcn_mfma_f32_16x16x32_bf16(a3, b1[3], accB, 0, 0, 0);
    }
    f32x4 z = accA + accB;
    #pragma unroll
    for (int i = 0; i < 4; ++i){
      int r = q * 4 + i;                               // C/D: row=(lane>>4)*4+reg
      float c1 = fmaxf(fmaf(dv, 1.0f + sigm(z[i]), -bias_c), 0.f);
      if (okc){
        out_his[(size_t)t * (BSZ * CA1N) + (size_t)(b0 + r) * CA1N + col] = c1;
        ca1b[r * SPB + col] = f2bf(c1);
        if (t == TLEN - 1) ca1f[r * SPF + col] = c1;
      }
    }
    __syncthreads();

    // ---- phase 2: delta = ca1 @ W2 (MFMA); ec5,ec3 elementwise update ----
    f32x4 acc2A = {0.f,0.f,0.f,0.f}, acc2B = {0.f,0.f,0.f,0.f};
    {
      bf16x8 a0 = *reinterpret_cast<const bf16x8*>(arow2 +  0 + q * 8);
      bf16x8 a1 = *reinterpret_cast<const bf16x8*>(arow2 + 32 + q * 8);
      bf16x8 a2 = *reinterpret_cast<const bf16x8*>(arow2 + 64 + q * 8);
      bf16x8 a3 = *reinterpret_cast<const bf16x8*>(arow2 + 96 + q * 8);
      acc2A = __builtin_amdgcn_mfma_f32_16x16x32_bf16(a0, b2[0], acc2A, 0, 0, 0);
      acc2B = __builtin_amdgcn_mfma_f32_16x16x32_bf16(a1, b2[1], acc2B, 0, 0, 0);
      acc2A = __builtin_amdgcn_mfma_f32_16x16x32_bf16(a2, b2[2], acc2A, 0, 0, 0);
      acc2B = __builtin_amdgcn_mfma_f32_16x16x32_bf16(a3, b2[3], acc2B, 0, 0, 0);
    }
    f32x4 z2 = acc2A + acc2B;
    int cu4 = *reinterpret_cast<const int*>(&cueT[t * BT + q * 4]); // 4 cue bytes
    #pragma unroll
    for (int i = 0; i < 4; ++i){
      int r = q * 4 + i;
      if (okc){
        float x  = ec5f[r * SPF + col] + z2[i];
        float e5 = fmaf(0.3f, sigm(fmaf(4.0f, x, -1.2f)), 0.69f);
        ec5f[r * SPF + col] = e5;
        int cu = (int)(signed char)(cu4 >> (8 * i));
        float sns = (cu == 1) ? cL : ((cu == -1) ? cR : 0.0f);
        float e3 = fmaf(e5, ec3f[r * SPF + col], sns);
        ec3f[r * SPF + col] = e3;
        ec3b[r * SPB + col] = f2bf(e3);
      }
    }
    __syncthreads();
  }

  // ---- epilogue: actCell = ca1_final @ Wca1act ; dump final states ----
  if (tid < BT * ACTN){
    int r = tid >> 1, a = tid & 1;
    float acc = 0.f;
    for (int jj = 0; jj < CA1N; ++jj)
      acc = fmaf(ca1f[r * SPF + jj], Wca1act[jj * ACTN + a], acc);
    out_act[(size_t)(b0 + r) * ACTN + a] = acc;
  }
  for (int idx = tid; idx < BT * ECN; idx += 512){
    int r = idx / ECN, c = idx - r * ECN;
    size_t g = (size_t)(b0 + r) * ECN + c;
    out_e3[g] = ec3f[r * SPF + c];
    out_e5[g] = ec5f[r * SPF + c];
    out_c1[g] = ca1f[r * SPF + c];
  }
}

extern "C" void kernel_launch(void* const* d_in, const int* in_sizes, int n_in,
                              void* d_out, int out_size, void* d_ws, size_t ws_size,
                              hipStream_t stream) {
  (void)in_sizes; (void)n_in; (void)out_size; (void)ws_size;
  const int*   cue_train = (const int*)  d_in[1];
  const float* ec3_last  = (const float*)d_in[2];
  const float* ec5_last  = (const float*)d_in[3];
  const float* cueL      = (const float*)d_in[5];
  const float* cueR      = (const float*)d_in[6];
  const float* Wec3ca1   = (const float*)d_in[7];
  const float* Wca3ca1   = (const float*)d_in[8];
  const float* Wca1ec5   = (const float*)d_in[9];
  const float* Wca1act   = (const float*)d_in[10];
  const float* ca1bias   = (const float*)d_in[11];
  float* out   = (float*)d_out;
  float* drive = (float*)d_ws;   // 100*100 fp32 = 40 KB scratch

  drive_kernel<<<TLEN, 128, 0, stream>>>(Wca3ca1, drive);
  rnn_kernel<<<BSZ / BT, 512, 0, stream>>>(cue_train, ec3_last, ec5_last,
                                           cueL, cueR, Wec3ca1, Wca1ec5,
                                           Wca1act, ca1bias, drive, out);
}

// Round 3
// 289.311 us; speedup vs baseline: 2.9288x; 1.0018x over previous
//
#include <hip/hip_runtime.h>

#define TLEN 100
#define ECN  100
#define CA1N 100
#define CA3N 100
#define BSZ  4096
#define ACTN 2
#define BT   16     // batch rows per block (= MFMA M)

typedef short bf16x8 __attribute__((ext_vector_type(8)));
typedef float f32x4  __attribute__((ext_vector_type(4)));

__device__ __forceinline__ unsigned short f2bf(float f){ // round-half-up bf16
  union { float f; unsigned int u; } c; c.f = f;
  return (unsigned short)((c.u + 0x8000u) >> 16);
}
__device__ __forceinline__ float fsigm(float x){ // 1/(1+exp(-x)), fast rcp
  float e = __expf(-x);
  return __builtin_amdgcn_rcpf(1.0f + e);
}

// ---- kernel 0: drive[t][j] = sum_k exp(-((t-c_k)/5)^2/2) * Wca3ca1[k][j] ----
__global__ void drive_kernel(const float* __restrict__ Wca3ca1, float* __restrict__ drive){
  __shared__ float ca3row[CA3N];
  const int t = blockIdx.x, tid = threadIdx.x;
  if (tid < CA3N){
    float c = (float)tid * (100.0f / 99.0f);   // linspace(0,100,100)
    float d = ((float)t - c) * 0.2f;           // /SIGMA=5
    ca3row[tid] = __expf(-0.5f * d * d);
  }
  __syncthreads();
  if (tid < CA1N){
    float acc = 0.f;
    for (int k = 0; k < CA3N; ++k) acc = fmaf(ca3row[k], Wca3ca1[k*CA1N + tid], acc);
    drive[t*CA1N + tid] = acc;
  }
}

// frag-linear bf16 A-shadow: element (m,k) lives at
//   ks*512 + (m + 16*((k>>3)&3))*8 + (k&7)   [shorts], ks = k>>5
// so a wave's ds_read_b128 at (ks*1024 + lane*16) bytes is lane-contiguous.

__global__ __launch_bounds__(512, 2)
void rnn_kernel(const int*   __restrict__ cue_train,
                const float* __restrict__ ec3_last,
                const float* __restrict__ ec5_last,
                const float* __restrict__ cueL,
                const float* __restrict__ cueR,
                const float* __restrict__ Wec3ca1,
                const float* __restrict__ Wca1ec5,
                const float* __restrict__ Wca1act,
                const float* __restrict__ ca1bias,
                const float* __restrict__ drive,
                float*       __restrict__ out)
{
  __shared__ __align__(16) unsigned short ec3b[4 * 64 * 8]; // frag-linear bf16 ec3
  __shared__ __align__(16) unsigned short ca1b[4 * 64 * 8]; // frag-linear bf16 ca1
  __shared__ __align__(16) float ca1f[BT * 132];            // final ca1 (epilogue)
  __shared__ signed char cueT[TLEN * BT];                   // cue transposed [t][r]

  const int tid = threadIdx.x;
  const int b0  = blockIdx.x * BT;

  float* out_act = out;
  float* out_his = out + (size_t)BSZ * ACTN;
  float* out_e3  = out_his + (size_t)TLEN * BSZ * CA1N;
  float* out_e5  = out_e3 + (size_t)BSZ * ECN;
  float* out_c1  = out_e5 + (size_t)BSZ * ECN;

  // --- zero frag shadows (pad rows k>=100 must stay 0 forever) ---
  for (int idx = tid; idx < 4 * 64 * 8; idx += 512){ ec3b[idx] = 0; ca1b[idx] = 0; }
  // --- stage cue ---
  for (int idx = tid; idx < BT * TLEN; idx += 512){
    int t = idx >> 4, r = idx & 15;
    cueT[idx] = (signed char)cue_train[(size_t)(b0 + r) * TLEN + t];
  }

  const int lane  = tid & 63;
  const int wv    = tid >> 6;          // wave id = N-tile id (0..7)
  const int col16 = lane & 15;
  const int q     = lane >> 4;         // quad
  const int col   = wv * 16 + col16;   // output column (CA1 ph1 / EC ph2)
  const bool okc  = (col < CA1N);
  const bool wactive = (wv < 7);       // wave 7: cols 112..127 all dead
  const int colc  = okc ? col : 0;

  // per-lane frag-write base (shorts): same formula for ec3 (k=col) and ca1 (k=col)
  const int abase = (col >> 5) * 512 + ((col >> 3) & 3) * 128 + (col & 7) + q * 32;

  // --- B-fragments in registers (bf16 weights) ---
  bf16x8 b1[4], b2[4];                 // B[k][n]: n=lane&15, k=ks*32+q*8+jj
  #pragma unroll
  for (int ks = 0; ks < 4; ++ks){
    #pragma unroll
    for (int jj = 0; jj < 8; ++jj){
      int k = ks * 32 + q * 8 + jj;
      float w1 = 0.f, w2 = 0.f;
      if (k < ECN && okc){
        w1 = Wec3ca1[k * CA1N + col];
        w2 = Wca1ec5[k * ECN  + col];
      }
      b1[ks][jj] = (short)f2bf(w1);
      b2[ks][jj] = (short)f2bf(w2);
    }
  }
  const float bias_c = okc ? ca1bias[col] : 0.f;
  const float cL = okc ? cueL[col] : 0.f;
  const float cR = okc ? cueR[col] : 0.f;

  __syncthreads();  // frag zero complete before state writes

  // --- fp32 state in registers (lane owns (r=q*4+i, col) — never shared) ---
  float ec3v[4], ec5v[4], c1[4] = {0.f,0.f,0.f,0.f};
  #pragma unroll
  for (int i = 0; i < 4; ++i){
    int r = q * 4 + i;
    float v3 = okc ? ec3_last[(size_t)(b0 + r) * ECN + col] : 0.f;
    float v5 = okc ? ec5_last[(size_t)(b0 + r) * ECN + col] : 0.f;
    ec3v[i] = v3; ec5v[i] = v5;
    if (okc) ec3b[abase + i * 8] = f2bf(v3);
  }
  __syncthreads();

  // running pointers
  const float* dp = drive + colc;                                   // += CA1N per step
  float* hp = out_his + (size_t)(b0 + q * 4) * CA1N + colc;         // += BSZ*CA1N per step

  const bf16x8* fe3 = (const bf16x8*)ec3b;   // chunk ks at index ks*64+lane
  const bf16x8* fc1 = (const bf16x8*)ca1b;

  for (int t = 0; t < TLEN; ++t){
    float dv  = *dp; dp += CA1N;                               // global, L2-hot
    int   cu4 = *(const int*)(cueT + t * BT + q * 4);          // 4 cue bytes (rows q*4..)

    // ---- phase 1: z = ec3 @ W1 ; ca1 = relu(dv*(1+sig(z)) - bias) ----
    if (wactive){
      f32x4 aA = {0.f,0.f,0.f,0.f}, aB = {0.f,0.f,0.f,0.f};
      bf16x8 a0 = fe3[  0 + lane];
      bf16x8 a1 = fe3[ 64 + lane];
      bf16x8 a2 = fe3[128 + lane];
      bf16x8 a3 = fe3[192 + lane];
      aA = __builtin_amdgcn_mfma_f32_16x16x32_bf16(a0, b1[0], aA, 0, 0, 0);
      aB = __builtin_amdgcn_mfma_f32_16x16x32_bf16(a1, b1[1], aB, 0, 0, 0);
      aA = __builtin_amdgcn_mfma_f32_16x16x32_bf16(a2, b1[2], aA, 0, 0, 0);
      aB = __builtin_amdgcn_mfma_f32_16x16x32_bf16(a3, b1[3], aB, 0, 0, 0);
      f32x4 z = aA + aB;
      float dmb = dv - bias_c;
      #pragma unroll
      for (int i = 0; i < 4; ++i){
        float v = fmaxf(fmaf(dv, fsigm(z[i]), dmb), 0.f);
        c1[i] = v;
        if (okc) ca1b[abase + i * 8] = f2bf(v);
      }
    }
    __syncthreads();

    // out_his stores AFTER the barrier: they drain under phase-2 compute,
    // so the phase-2 barrier's vmcnt(0) is nearly free.
    if (okc){
      hp[0 * CA1N] = c1[0];
      hp[1 * CA1N] = c1[1];
      hp[2 * CA1N] = c1[2];
      hp[3 * CA1N] = c1[3];
    }
    hp += (size_t)BSZ * CA1N;

    // ---- phase 2: z2 = ca1 @ W2 ; ec5/ec3 register update ----
    if (wactive){
      f32x4 aA = {0.f,0.f,0.f,0.f}, aB = {0.f,0.f,0.f,0.f};
      bf16x8 a0 = fc1[  0 + lane];
      bf16x8 a1 = fc1[ 64 + lane];
      bf16x8 a2 = fc1[128 + lane];
      bf16x8 a3 = fc1[192 + lane];
      aA = __builtin_amdgcn_mfma_f32_16x16x32_bf16(a0, b2[0], aA, 0, 0, 0);
      aB = __builtin_amdgcn_mfma_f32_16x16x32_bf16(a1, b2[1], aB, 0, 0, 0);
      aA = __builtin_amdgcn_mfma_f32_16x16x32_bf16(a2, b2[2], aA, 0, 0, 0);
      aB = __builtin_amdgcn_mfma_f32_16x16x32_bf16(a3, b2[3], aB, 0, 0, 0);
      f32x4 z2 = aA + aB;
      #pragma unroll
      for (int i = 0; i < 4; ++i){
        float x  = ec5v[i] + z2[i];
        float e5 = fmaf(0.3f, fsigm(fmaf(4.0f, x, -1.2f)), 0.69f);
        ec5v[i] = e5;
        int cu = (cu4 >> (8 * i)) & 0xff;                 // -1 -> 0xff
        float sns = (cu == 1) ? cL : ((cu == 0xff) ? cR : 0.0f);
        float e3 = fmaf(e5, ec3v[i], sns);
        ec3v[i] = e3;
        if (okc) ec3b[abase + i * 8] = f2bf(e3);
      }
    }
    __syncthreads();
  }

  // ---- epilogue: dump final states from registers ----
  if (okc){
    #pragma unroll
    for (int i = 0; i < 4; ++i){
      int r = q * 4 + i;
      size_t g = (size_t)(b0 + r) * ECN + col;
      out_e3[g] = ec3v[i];
      out_e5[g] = ec5v[i];
      out_c1[g] = c1[i];
      ca1f[r * 132 + col] = c1[i];
    }
  }
  __syncthreads();

  // actCell = ca1_final @ Wca1act
  if (tid < BT * ACTN){
    int r = tid >> 1, a = tid & 1;
    float acc = 0.f;
    for (int jj = 0; jj < CA1N; ++jj)
      acc = fmaf(ca1f[r * 132 + jj], Wca1act[jj * ACTN + a], acc);
    out_act[(size_t)(b0 + r) * ACTN + a] = acc;
  }
}

extern "C" void kernel_launch(void* const* d_in, const int* in_sizes, int n_in,
                              void* d_out, int out_size, void* d_ws, size_t ws_size,
                              hipStream_t stream) {
  (void)in_sizes; (void)n_in; (void)out_size; (void)ws_size;
  const int*   cue_train = (const int*)  d_in[1];
  const float* ec3_last  = (const float*)d_in[2];
  const float* ec5_last  = (const float*)d_in[3];
  const float* cueL      = (const float*)d_in[5];
  const float* cueR      = (const float*)d_in[6];
  const float* Wec3ca1   = (const float*)d_in[7];
  const float* Wca3ca1   = (const float*)d_in[8];
  const float* Wca1ec5   = (const float*)d_in[9];
  const float* Wca1act   = (const float*)d_in[10];
  const float* ca1bias   = (const float*)d_in[11];
  float* out   = (float*)d_out;
  float* drive = (float*)d_ws;   // 100*100 fp32 = 40 KB scratch

  drive_kernel<<<TLEN, 128, 0, stream>>>(Wca3ca1, drive);
  rnn_kernel<<<BSZ / BT, 512, 0, stream>>>(cue_train, ec3_last, ec5_last,
                                           cueL, cueR, Wec3ca1, Wca1ec5,
                                           Wca1act, ca1bias, drive, out);
}